// Round 1
// 8267.046 us; speedup vs baseline: 2.2373x; 2.2373x over previous
//
#include <hip/hip_runtime.h>

#define T_STEPS 2048
#define BATCH 8
#define HID 1024

// ws layout:
//   floats [0, 50331648)      x_proj repacked [t][b][gate][j]: ((t*8+b)*3+g)*1024 + j
//   byte 201326592 (=192MiB): h double buffer, 2 x 8192 u64 {tag(hi32), f32 h(lo32)}
//                             slot = parity*8192 + b*1024 + j; production step s -> buffer s&1,
//                             tag = s+1. 128 KiB total. (ws poison 0xAAAAAAAA never matches a tag.)
//
// R-batch-split: scan re-decomposed into 4 independent batch-groups x 64 blocks.
// Block owns (2 batches x 16 j) instead of (8 batches x 4 j): staging volume/block
// 64KB -> 16KB, sync domain 256 -> 64 blocks, hv LDS reads 128 -> 32/lane,
// value-folding reduce 144 -> 30 shuffles, j-contiguous out/xproj stores (kills the
// RFO write-amplification that showed as FETCH=1.13GB / WRITE=671MB).
#define XPROJ_F 50331648ull
#define HBUF64_BYTE_OFF 201326592ull

__device__ __forceinline__ float sigmoidf_(float x) {
    return 1.0f / (1.0f + __expf(-x));
}

// Relaxed AGENT-scope atomics lower to global_load/store ... sc1 — they read/
// write the Infinity Cache (the inter-XCD coherence point) with NO L2
// writeback/invalidate. An aligned 8B store is single-copy atomic, so the
// {tag, value} packet is self-validating: no flags, no fences, no drains.
__device__ __forceinline__ unsigned long long ld_u64_agent(const unsigned long long* p) {
    return __hip_atomic_load(p, __ATOMIC_RELAXED, __HIP_MEMORY_SCOPE_AGENT);
}
__device__ __forceinline__ void st_u64_agent(unsigned long long* p, unsigned long long v) {
    __hip_atomic_store(p, v, __ATOMIC_RELAXED, __HIP_MEMORY_SCOPE_AGENT);
}

// ---------------- Phase 1: x_proj = x @ W_ih^T + b_ih ----------------
// 128x128 tile, BK=16, 256 threads, 8x8 micro-tile. Epilogue writes the
// [t][b][g][j] layout the scan wants (j-contiguous -> two float4 stores/row).
__global__ __launch_bounds__(256) void gemm_xproj(
        const float* __restrict__ x, const float* __restrict__ Wih,
        const float* __restrict__ bih, float* __restrict__ xproj) {
    __shared__ float a_lds[16][128];  // [k][m]
    __shared__ float b_lds[16][128];  // [k][n]
    const int tid = threadIdx.x;
    const int m0 = blockIdx.x * 128;
    const int n0 = blockIdx.y * 128;
    const int tx = tid & 15, ty = tid >> 4;

    float acc[8][8];
#pragma unroll
    for (int i = 0; i < 8; i++)
#pragma unroll
        for (int jj = 0; jj < 8; jj++) acc[i][jj] = 0.f;

    for (int k0 = 0; k0 < 1024; k0 += 16) {
#pragma unroll
        for (int l = 0; l < 2; l++) {
            const int c = tid + l * 256;
            const int row = c >> 2;
            const int f4 = c & 3;
            float4 av = *reinterpret_cast<const float4*>(
                x + (size_t)(m0 + row) * 1024 + k0 + f4 * 4);
            float4 bv = *reinterpret_cast<const float4*>(
                Wih + (size_t)(n0 + row) * 1024 + k0 + f4 * 4);
            a_lds[f4 * 4 + 0][row] = av.x; a_lds[f4 * 4 + 1][row] = av.y;
            a_lds[f4 * 4 + 2][row] = av.z; a_lds[f4 * 4 + 3][row] = av.w;
            b_lds[f4 * 4 + 0][row] = bv.x; b_lds[f4 * 4 + 1][row] = bv.y;
            b_lds[f4 * 4 + 2][row] = bv.z; b_lds[f4 * 4 + 3][row] = bv.w;
        }
        __syncthreads();
#pragma unroll
        for (int kk = 0; kk < 16; kk++) {
            float a[8], b[8];
            *reinterpret_cast<float4*>(&a[0]) =
                *reinterpret_cast<float4*>(&a_lds[kk][ty * 8]);
            *reinterpret_cast<float4*>(&a[4]) =
                *reinterpret_cast<float4*>(&a_lds[kk][ty * 8 + 4]);
            *reinterpret_cast<float4*>(&b[0]) =
                *reinterpret_cast<float4*>(&b_lds[kk][tx * 8]);
            *reinterpret_cast<float4*>(&b[4]) =
                *reinterpret_cast<float4*>(&b_lds[kk][tx * 8 + 4]);
#pragma unroll
            for (int i = 0; i < 8; i++)
#pragma unroll
                for (int jj = 0; jj < 8; jj++)
                    acc[i][jj] = fmaf(a[i], b[jj], acc[i][jj]);
        }
        __syncthreads();
    }

    float bias[8];
    *reinterpret_cast<float4*>(&bias[0]) =
        *reinterpret_cast<const float4*>(bih + n0 + tx * 8);
    *reinterpret_cast<float4*>(&bias[4]) =
        *reinterpret_cast<const float4*>(bih + n0 + tx * 8 + 4);
    // m = b*T + t; 128-row m-tiles never straddle a batch (T=2048 % 128 == 0).
    // n-tile (128 wide) never straddles a gate (1024 % 128 == 0).
    const int n_base = n0 + tx * 8;
    const int g = n_base >> 10;
    const int j0 = n_base & 1023;
#pragma unroll
    for (int i = 0; i < 8; i++) {
        const int m = m0 + ty * 8 + i;
        const int b = m >> 11;        // m / 2048
        const int t = m & 2047;
        float* dst = xproj + (((size_t)t * 8 + b) * 3 + g) * 1024 + j0;
        float4 r0 = {acc[i][0] + bias[0], acc[i][1] + bias[1],
                     acc[i][2] + bias[2], acc[i][3] + bias[3]};
        float4 r1 = {acc[i][4] + bias[4], acc[i][5] + bias[5],
                     acc[i][6] + bias[6], acc[i][7] + bias[7]};
        *reinterpret_cast<float4*>(dst) = r0;
        *reinterpret_cast<float4*>(dst + 4) = r1;
    }
}

// ---------------- Phase 2: sequential GRU scan, batch-partitioned ----------------
// 256 blocks x 256 threads, co-resident (1 block/CU).
// group = bid>>6 (4 groups x 64 blocks) owns batches {2g, 2g+1} — groups are
// fully independent sync domains. Block bid owns j in [gb*16, gb*16+16),
// gb = bid&63; wave owns 4 j. Per wave: 4 j x 2 b x 3 gates = 24 dot products,
// K split 64-way across lanes (384 FMA/lane, W_hh fragment = 192 VGPR).
// Per step: prefetch gx -> 8 pipelined tagged u64 loads (own group's 2 batches
// only) -> retry stale -> LDS stage (double-buffered hshare) -> sync ->
// matvec -> value-folding reduce (30 shuffles) -> gates on lanes 0..7 ->
// tagged u64 h store + j-contiguous out store.
__global__ __launch_bounds__(256, 1) void gru_scan(
        const float* __restrict__ Whh, const float* __restrict__ bhh,
        const float* __restrict__ xproj, float* __restrict__ out,
        unsigned long long* __restrict__ hbuf64) {
    __shared__ float hshare[2][2 * HID];   // 16 KB, [parity][b_local][j]
    const int tid = threadIdx.x;
    const int bid = blockIdx.x;
    const int wave = tid >> 6;
    const int lane = tid & 63;
    const int group = bid >> 6;           // 0..3
    const int gb = bid & 63;              // block within group
    const int b0 = group * 2;             // first of this group's 2 batches
    const int jbase = gb * 16 + wave * 4; // wave's 4 j values

    // loop-invariant W_hh fragment: rows g*1024 + (jbase+jj), k = lane + 64*i
    float wf[3][4][16];
#pragma unroll
    for (int g = 0; g < 3; g++)
#pragma unroll
        for (int jj = 0; jj < 4; jj++)
#pragma unroll
            for (int i = 0; i < 16; i++)
                wf[g][jj][i] =
                    Whh[(size_t)(g * 1024 + jbase + jj) * 1024 + lane + 64 * i];

    // lane l<8 owns (jj = l>>1, bb = l&1) -> j_l, b_l
    const int jj_l = lane >> 1;
    const int bb_l = lane & 1;
    const int j_l = jbase + jj_l;
    const int b_l = b0 + bb_l;
    float bh0 = 0.f, bh1 = 0.f, bh2 = 0.f;
    if (lane < 8) {
        bh0 = bhh[j_l];
        bh1 = bhh[1024 + j_l];
        bh2 = bhh[2048 + j_l];
    }

    // ---- t = 0: h_prev = 0 -> g_h = b_hh ----
    if (lane < 8) {
        const size_t xb = ((size_t)0 * 8 + b_l) * 3 * 1024 + j_l;
        const float gxr = xproj[xb];
        const float gxz = xproj[xb + 1024];
        const float gxn = xproj[xb + 2048];
        const float r = sigmoidf_(gxr + bh0);
        const float z = sigmoidf_(gxz + bh1);
        const float n = tanhf(gxn + r * bh2);
        const float hnew = (1.f - z) * n;
        // buffer parity 0, tag 1
        st_u64_agent(hbuf64 + (size_t)b_l * HID + j_l,
                     ((unsigned long long)1u << 32) | __float_as_uint(hnew));
        out[(size_t)b_l * T_STEPS * HID + j_l] = hnew;
    }

    for (int t = 1; t < T_STEPS; t++) {
        // prefetch gx (plain cached loads, overlap the staging latency)
        float gxr = 0.f, gxz = 0.f, gxn = 0.f;
        if (lane < 8) {
            const size_t xb = ((size_t)t * 8 + b_l) * 3 * 1024 + j_l;
            gxr = xproj[xb];
            gxz = xproj[xb + 1024];
            gxn = xproj[xb + 2048];
        }

        // ---- stage h(t-1) for this group's 2 batches: 8 tagged u64 loads ----
        const int par = (t - 1) & 1;
        const unsigned long long* src =
            hbuf64 + (size_t)par * 8192 + (size_t)b0 * HID;
        const unsigned expect = (unsigned)t;   // tag of h produced at step t-1
        unsigned long long v[8];
#pragma unroll
        for (int i = 0; i < 8; i++)
            v[i] = ld_u64_agent(src + tid + 256 * i);
        for (;;) {
            unsigned bad = 0;
#pragma unroll
            for (int i = 0; i < 8; i++)
                bad |= (unsigned)(v[i] >> 32) ^ expect;
            if (bad == 0) break;
            __builtin_amdgcn_s_sleep(1);
#pragma unroll
            for (int i = 0; i < 8; i++)
                if ((unsigned)(v[i] >> 32) != expect)
                    v[i] = ld_u64_agent(src + tid + 256 * i);
        }
#pragma unroll
        for (int i = 0; i < 8; i++)
            hshare[par][tid + 256 * i] = __uint_as_float((unsigned)v[i]);
        __syncthreads();   // whole block validated + staged h(t-1)
        // (no trailing barrier needed: next step stages into the other half)

        const float hprev = (lane < 8) ? hshare[par][bb_l * HID + j_l] : 0.f;

        float acc[3][8];   // [g][jj*2+bb]
#pragma unroll
        for (int g = 0; g < 3; g++)
#pragma unroll
            for (int q = 0; q < 8; q++) acc[g][q] = 0.f;
#pragma unroll
        for (int bb = 0; bb < 2; bb++) {
            float hv[16];
#pragma unroll
            for (int i = 0; i < 16; i++)
                hv[i] = hshare[par][bb * HID + lane + 64 * i];
#pragma unroll
            for (int g = 0; g < 3; g++)
#pragma unroll
                for (int jj = 0; jj < 4; jj++)
#pragma unroll
                    for (int i = 0; i < 16; i++)
                        acc[g][jj * 2 + bb] =
                            fmaf(wf[g][jj][i], hv[i], acc[g][jj * 2 + bb]);
        }

        // ---- value-folding reduce over the 64-way K split ----
        // After 3 fold stages + 3 butterfly stages, lane l holds the complete
        // sums for jb = l&7. 30 shuffles total (vs 144 for full butterfly).
        float a4[3][4];
#pragma unroll
        for (int g = 0; g < 3; g++)
#pragma unroll
            for (int k = 0; k < 4; k++) {
                const float e = acc[g][2 * k], o = acc[g][2 * k + 1];
                const float give = (lane & 1) ? e : o;
                const float keep = (lane & 1) ? o : e;
                a4[g][k] = keep + __shfl_xor(give, 1);
            }
        float a2[3][2];
#pragma unroll
        for (int g = 0; g < 3; g++)
#pragma unroll
            for (int k = 0; k < 2; k++) {
                const float e = a4[g][2 * k], o = a4[g][2 * k + 1];
                const float give = (lane & 2) ? e : o;
                const float keep = (lane & 2) ? o : e;
                a2[g][k] = keep + __shfl_xor(give, 2);
            }
        float a1[3];
#pragma unroll
        for (int g = 0; g < 3; g++) {
            const float e = a2[g][0], o = a2[g][1];
            const float give = (lane & 4) ? e : o;
            const float keep = (lane & 4) ? o : e;
            a1[g] = keep + __shfl_xor(give, 4);
        }
#pragma unroll
        for (int m = 8; m <= 32; m <<= 1)
#pragma unroll
            for (int g = 0; g < 3; g++) a1[g] += __shfl_xor(a1[g], m);

        if (lane < 8) {
            const float r = sigmoidf_(gxr + a1[0] + bh0);
            const float z = sigmoidf_(gxz + a1[1] + bh1);
            const float n = tanhf(gxn + r * (a1[2] + bh2));
            const float hnew = (1.f - z) * n + z * hprev;
            // single self-validating packet: {tag = t+1, h}
            st_u64_agent(hbuf64 + (size_t)(t & 1) * 8192 + (size_t)b_l * HID + j_l,
                         ((unsigned long long)(unsigned)(t + 1) << 32) |
                             __float_as_uint(hnew));
            out[((size_t)b_l * T_STEPS + t) * HID + j_l] = hnew;
        }
    }
}

extern "C" void kernel_launch(void* const* d_in, const int* in_sizes, int n_in,
                              void* d_out, int out_size, void* d_ws,
                              size_t ws_size, hipStream_t stream) {
    const float* x    = (const float*)d_in[0];
    const float* Wih  = (const float*)d_in[1];
    const float* bih  = (const float*)d_in[2];
    const float* Whh  = (const float*)d_in[3];
    const float* bhh  = (const float*)d_in[4];
    float* outp = (float*)d_out;

    float* xproj = (float*)d_ws;
    unsigned long long* hbuf64 =
        (unsigned long long*)((char*)d_ws + HBUF64_BYTE_OFF);

    dim3 g1(128, 24);   // M/128, N/128
    gemm_xproj<<<g1, 256, 0, stream>>>(x, Wih, bih, xproj);
    gru_scan<<<256, 256, 0, stream>>>(Whh, bhh, xproj, outp, hbuf64);
}